// Round 9
// baseline (85.792 us; speedup 1.0000x reference)
//
#include <hip/hip_runtime.h>
#include <hip/hip_bf16.h>

typedef __attribute__((ext_vector_type(8))) short short8;
typedef __attribute__((ext_vector_type(4))) float f32x4;

#define IN_F 512
#define OUT_F 512
#define BM 64
#define BN 512
#define BK 64
#define THREADS 512
#define PHI_STEPS 64
#define NSTEPS 72
#define KSPLIT 2
#define IMG_CHUNKS 4096                  // (512 n) x (8 slots) 16B chunks per step
#define A_SH (BM * BK)                   // 8 KB
#define B_SH (BN * BK)                   // 64 KB
#define PART_ELEMS (8192 * OUT_F)

__device__ __forceinline__ short f2bf(float f) {
  __hip_bfloat16 h = __float2bfloat16(f);
  return __builtin_bit_cast(short, h);
}

__device__ __forceinline__ void glds16(const void* g, void* l) {
  __builtin_amdgcn_global_load_lds(
      (const __attribute__((address_space(1))) unsigned int*)g,
      (__attribute__((address_space(3))) unsigned int*)l, 16, 0, 0);
}

__device__ __forceinline__ float bsrc(const float* __restrict__ w,
                                      const float* __restrict__ sb,
                                      int k, int col) {
  return (k < IN_F * 8) ? w[(size_t)k * OUT_F + col]
                        : sb[(size_t)(k - IN_F * 8) * OUT_F + col];
}

// bf16 B-images in exact LDS tile byte order: chunk ci = n*8+slot, slot = oct^(n&7),
// element j -> B[k = s*64 + oct*8 + j][n].
__global__ void __launch_bounds__(256) prep_b(const float* __restrict__ w,
                                              const float* __restrict__ sb,
                                              short* __restrict__ img) {
  const int D = blockIdx.x * 256 + threadIdx.x;
  const int ci = D & (IMG_CHUNKS - 1);
  const int s = D >> 12;
  const int n = ci >> 3, slot = ci & 7;
  const int oct = slot ^ (n & 7);
  short8 v;
#pragma unroll
  for (int j = 0; j < 8; ++j) v[j] = f2bf(bsrc(w, sb, s * 64 + oct * 8 + j, n));
  *(short8*)&img[(size_t)D * 8] = v;
}

__global__ void __launch_bounds__(256) reduce_add(const float* __restrict__ part,
                                                  float* __restrict__ out) {
  const int n4 = PART_ELEMS / 4;
  const float4* p4 = (const float4*)part;
  float4* o4 = (float4*)out;
  for (int i = blockIdx.x * 256 + threadIdx.x; i < n4; i += gridDim.x * 256) {
    float4 a = o4[i];
    const float4 b = p4[i];
    a.x += b.x; a.y += b.y; a.z += b.z; a.w += b.w;
    o4[i] = a;
  }
}

template <int KS, bool PREB>
__global__ void __launch_bounds__(THREADS, 2) kan_main(
    const float* __restrict__ x, const float* __restrict__ rw,
    const float* __restrict__ rc, const float* __restrict__ w,
    const float* __restrict__ bias, const float* __restrict__ sb,
    const short* __restrict__ bimg, float* __restrict__ out,
    float* __restrict__ part) {
  constexpr int SPLC = NSTEPS / KS;
  __shared__ __align__(16) short A_lds[2][A_SH];   // 16 KB
  __shared__ __align__(16) short B_lds[2][B_SH];   // 128 KB

  const int t = threadIdx.x, lane = t & 63, wid = t >> 6;
  const int l15 = lane & 15, kb = lane >> 4;
  const int m0 = blockIdx.x * BM;
  const int ks = (KS == 2) ? blockIdx.y : 0;
  const int s0 = ks * SPLC;

  const int a_il = t & 7;        // k-octet
  const int a_m = t >> 3;        // A row 0..63
  const float c2 = -10.2591705f; // -(8/3)^2 * log2(e)

  f32x4 acc[4][4];
#pragma unroll
  for (int i = 0; i < 4; ++i)
#pragma unroll
    for (int j = 0; j < 4; ++j) acc[i][j] = (f32x4){0.f, 0.f, 0.f, 0.f};

  // ---- parity-named x prefetch sets (no runtime-indexed reg arrays) ----
  float xs0, xs1;                 // phi x (scalar per A-thread)
  float4 cx0a, cx0b, cx1a, cx1b;  // cos x (float4 pair)

  auto loadX = [&](int s2, int set) {
    if (s2 < PHI_STEPS) {
      const float v = x[(size_t)(m0 + a_m) * IN_F + s2 * 8 + a_il];
      if (set == 0) xs0 = v; else xs1 = v;
    } else {
      const float* xp = x + (size_t)(m0 + a_m) * IN_F + (s2 - PHI_STEPS) * 64 + a_il * 8;
      const float4 u = *(const float4*)xp;
      const float4 v = *(const float4*)(xp + 4);
      if (set == 0) { cx0a = u; cx0b = v; } else { cx1a = u; cx1b = v; }
    }
  };

  auto stageB = [&](int s, short* __restrict__ Bd) {
    if (PREB) {
      const short* src = bimg + ((size_t)s * IMG_CHUNKS + t) * 8;
#pragma unroll
      for (int c = 0; c < 8; ++c)
        glds16(src + (size_t)c * 512 * 8, Bd + c * 4096 + wid * 512);
    } else {
#pragma unroll
      for (int c = 0; c < 8; ++c) {
        const int ci = c * 512 + t;
        const int n = ci >> 3, slot = ci & 7, oct = slot ^ (n & 7);
        short8 v;
#pragma unroll
        for (int j = 0; j < 8; ++j) v[j] = f2bf(bsrc(w, sb, s * 64 + oct * 8 + j, n));
        *(short8*)&Bd[ci * 8] = v;
      }
    }
  };

  // exp/cos + pack + ds_write; all operands already in registers.
  auto writeA = [&](int s1, int set, short* __restrict__ Ad,
                    const float4& r0, const float4& r1,
                    const float4& q0, const float4& q1) {
    short8 av;
    if (s1 < PHI_STEPS) {
      const float xv = (set == 0) ? xs0 : xs1;
      const float rwv[8] = {r0.x, r0.y, r0.z, r0.w, r1.x, r1.y, r1.z, r1.w};
      const float rcv[8] = {q0.x, q0.y, q0.z, q0.w, q1.x, q1.y, q1.z, q1.w};
#pragma unroll
      for (int b = 0; b < 8; ++b) {
        const float z = fmaf(xv, rwv[b], -rcv[b]);
        av[b] = f2bf(exp2f(c2 * z * z));
      }
    } else {
      const float4 u = (set == 0) ? cx0a : cx1a;
      const float4 v = (set == 0) ? cx0b : cx1b;
      av[0] = f2bf(__cosf(u.x)); av[1] = f2bf(__cosf(u.y));
      av[2] = f2bf(__cosf(u.z)); av[3] = f2bf(__cosf(u.w));
      av[4] = f2bf(__cosf(v.x)); av[5] = f2bf(__cosf(v.y));
      av[6] = f2bf(__cosf(v.z)); av[7] = f2bf(__cosf(v.w));
    }
    *(short8*)&Ad[a_m * BK + (a_il ^ (a_m & 7)) * 8] = av;
  };

  auto mfma_half = [&](const short* __restrict__ Ab, const short* __restrict__ Bb,
                       int kk) {
    const int sk = kk * 4 + kb;
    short8 af[4], bf[4];
#pragma unroll
    for (int mi = 0; mi < 4; ++mi) {
      const int r = mi * 16 + l15;
      af[mi] = *(const short8*)&Ab[r * BK + (sk ^ (r & 7)) * 8];
    }
#pragma unroll
    for (int ni = 0; ni < 4; ++ni) {
      const int n = wid * 64 + ni * 16 + l15;
      bf[ni] = *(const short8*)&Bb[n * BK + (sk ^ (n & 7)) * 8];
    }
#pragma unroll
    for (int mi = 0; mi < 4; ++mi)
#pragma unroll
      for (int ni = 0; ni < 4; ++ni)
        acc[mi][ni] = __builtin_amdgcn_mfma_f32_16x16x32_bf16(
            af[mi], bf[ni], acc[mi][ni], 0, 0, 0);
  };

  // ---------------- prologue: build step s0 (always a phi step) ----------------
  stageB(s0, B_lds[0]);
  {
    const int feat = s0 * 8 + a_il;
    const float xv = x[(size_t)(m0 + a_m) * IN_F + feat];
    const float4 r0 = *(const float4*)(rw + feat * 8);
    const float4 r1 = *(const float4*)(rw + feat * 8 + 4);
    const float4 q0 = *(const float4*)(rc + feat * 8);
    const float4 q1 = *(const float4*)(rc + feat * 8 + 4);
    const float rwv[8] = {r0.x, r0.y, r0.z, r0.w, r1.x, r1.y, r1.z, r1.w};
    const float rcv[8] = {q0.x, q0.y, q0.z, q0.w, q1.x, q1.y, q1.z, q1.w};
    short8 av;
#pragma unroll
    for (int b = 0; b < 8; ++b) {
      const float z = fmaf(xv, rwv[b], -rcv[b]);
      av[b] = f2bf(exp2f(c2 * z * z));
    }
    *(short8*)&A_lds[0][a_m * BK + (a_il ^ (a_m & 7)) * 8] = av;
  }
  loadX(s0 + 1, 1);   // consumed by writeA at si=0 (set 1)
  __syncthreads();

  // ---------------- main loop: 2 steps per trip, compile-time parity ----------
#define KAN_STEP(SI, CUR)                                                        \
  {                                                                              \
    const int si = (SI), s = s0 + si;                                            \
    const bool doW = (si + 1 < SPLC);                                            \
    if (doW) stageB(s + 1, B_lds[CUR ^ 1]);                                      \
    if (si + 2 < SPLC) loadX(s + 2, (CUR));                                      \
    float4 r0, r1, q0, q1;                                                       \
    if (doW && (s + 1) < PHI_STEPS) {                                            \
      const int feat = (s + 1) * 8 + a_il;                                       \
      r0 = *(const float4*)(rw + feat * 8);                                      \
      r1 = *(const float4*)(rw + feat * 8 + 4);                                  \
      q0 = *(const float4*)(rc + feat * 8);                                      \
      q1 = *(const float4*)(rc + feat * 8 + 4);                                  \
    }                                                                            \
    mfma_half(A_lds[CUR], B_lds[CUR], 0);                                        \
    if (doW) writeA(s + 1, (CUR) ^ 1, A_lds[CUR ^ 1], r0, r1, q0, q1);           \
    mfma_half(A_lds[CUR], B_lds[CUR], 1);                                        \
    __syncthreads();                                                             \
  }

  for (int so = 0; so < SPLC / 2; ++so) {
    KAN_STEP(2 * so, 0)
    KAN_STEP(2 * so + 1, 1)
  }
#undef KAN_STEP

  // ---------------- epilogue ----------------
#pragma unroll
  for (int ni = 0; ni < 4; ++ni) {
    const int col = wid * 64 + ni * 16 + l15;
    const float bb = (KS == 1 || ks == 0) ? bias[col] : 0.f;
#pragma unroll
    for (int mi = 0; mi < 4; ++mi) {
      const int rb = m0 + mi * 16 + kb * 4;
#pragma unroll
      for (int r4 = 0; r4 < 4; ++r4) {
        const size_t idx = (size_t)(rb + r4) * OUT_F + col;
        if (KS == 1 || ks == 0) out[idx] = acc[mi][ni][r4] + bb;
        else                    part[idx] = acc[mi][ni][r4];
      }
    }
  }
}

extern "C" void kernel_launch(void* const* d_in, const int* in_sizes, int n_in,
                              void* d_out, int out_size, void* d_ws, size_t ws_size,
                              hipStream_t stream) {
  const float* x    = (const float*)d_in[0];
  const float* rw   = (const float*)d_in[1];
  const float* rc   = (const float*)d_in[2];
  const float* w    = (const float*)d_in[3];
  const float* bias = (const float*)d_in[4];
  const float* sb   = (const float*)d_in[5];
  float* out = (float*)d_out;

  const int nrows = in_sizes[0] / IN_F;  // 8192

  const size_t img_bytes  = (size_t)NSTEPS * IMG_CHUNKS * 16;    // 4.72 MB
  const size_t part_bytes = (size_t)PART_ELEMS * sizeof(float);  // 16.8 MB
  const int img_chunks_total = NSTEPS * IMG_CHUNKS;

  if (ws_size >= img_bytes + part_bytes) {
    short* img = (short*)d_ws;
    float* part = (float*)((char*)d_ws + img_bytes);
    prep_b<<<img_chunks_total / 256, 256, 0, stream>>>(w, sb, img);
    dim3 grid(nrows / BM, KSPLIT);       // (128, 2) = 256 blocks, 1/CU
    kan_main<KSPLIT, true><<<grid, THREADS, 0, stream>>>(x, rw, rc, w, bias, sb,
                                                         img, out, part);
    reduce_add<<<2048, 256, 0, stream>>>(part, out);
  } else if (ws_size >= part_bytes) {
    float* part = (float*)d_ws;
    dim3 grid(nrows / BM, KSPLIT);
    kan_main<KSPLIT, false><<<grid, THREADS, 0, stream>>>(x, rw, rc, w, bias, sb,
                                                          nullptr, out, part);
    reduce_add<<<2048, 256, 0, stream>>>(part, out);
  } else {
    dim3 grid(nrows / BM, 1);
    kan_main<1, false><<<grid, THREADS, 0, stream>>>(x, rw, rc, w, bias, sb,
                                                     nullptr, out, nullptr);
  }
}

// Round 10
// 83.792 us; speedup vs baseline: 1.0239x; 1.0239x over previous
//
#include <hip/hip_runtime.h>
#include <hip/hip_bf16.h>

typedef __attribute__((ext_vector_type(8))) short short8;
typedef __attribute__((ext_vector_type(4))) float f32x4;

#define IN_F 512
#define OUT_F 512
#define BM 128
#define BN 512
#define BK 64
#define THREADS 512
#define PHI_STEPS 64
#define NSTEPS 72
#define IMG_CHUNKS 4096                  // (512 n) x (8 slots) 16B chunks per step
#define A_SH (BM * BK)                   // 16 KB
#define B_SH (BN * BK)                   // 64 KB
#define PART_ELEMS (8192 * OUT_F)        // one f32 partial plane (16.8 MB)

__device__ __forceinline__ short f2bf(float f) {
  __hip_bfloat16 h = __float2bfloat16(f);
  return __builtin_bit_cast(short, h);
}

__device__ __forceinline__ void glds16(const void* g, void* l) {
  // 16B global->LDS; LDS base wave-uniform (HW adds lane*16); global src per-lane.
  __builtin_amdgcn_global_load_lds(
      (const __attribute__((address_space(1))) unsigned int*)g,
      (__attribute__((address_space(3))) unsigned int*)l, 16, 0, 0);
}

__device__ __forceinline__ float bsrc(const float* __restrict__ w,
                                      const float* __restrict__ sb,
                                      int k, int col) {
  return (k < IN_F * 8) ? w[(size_t)k * OUT_F + col]
                        : sb[(size_t)(k - IN_F * 8) * OUT_F + col];
}

// bf16 B-images in exact LDS tile byte order: chunk ci = n*8+slot, slot = oct^(n&7),
// element j -> B[k = s*64 + oct*8 + j][n].
__global__ void __launch_bounds__(256) prep_b(const float* __restrict__ w,
                                              const float* __restrict__ sb,
                                              short* __restrict__ img) {
  const int D = blockIdx.x * 256 + threadIdx.x;
  const int ci = D & (IMG_CHUNKS - 1);
  const int s = D >> 12;
  const int n = ci >> 3, slot = ci & 7;
  const int oct = slot ^ (n & 7);
  short8 v;
#pragma unroll
  for (int j = 0; j < 8; ++j) v[j] = f2bf(bsrc(w, sb, s * 64 + oct * 8 + j, n));
  *(short8*)&img[(size_t)D * 8] = v;
}

// out += p0 (+ p1 + p2)
template <int NPLANES>
__global__ void __launch_bounds__(256) reduce_add(const float* __restrict__ part,
                                                  float* __restrict__ out) {
  const int n4 = PART_ELEMS / 4;
  const float4* p0 = (const float4*)part;
  const float4* p1 = (const float4*)(part + PART_ELEMS);
  const float4* p2 = (const float4*)(part + 2 * (size_t)PART_ELEMS);
  float4* o4 = (float4*)out;
  for (int i = blockIdx.x * 256 + threadIdx.x; i < n4; i += gridDim.x * 256) {
    float4 a = o4[i];
    const float4 b = p0[i];
    a.x += b.x; a.y += b.y; a.z += b.z; a.w += b.w;
    if (NPLANES >= 2) {
      const float4 c = p1[i];
      a.x += c.x; a.y += c.y; a.z += c.z; a.w += c.w;
    }
    if (NPLANES >= 3) {
      const float4 d = p2[i];
      a.x += d.x; a.y += d.y; a.z += d.z; a.w += d.w;
    }
    o4[i] = a;
  }
}

template <int KS, bool PREB>
__global__ void __launch_bounds__(THREADS, 2) kan_main(
    const float* __restrict__ x, const float* __restrict__ rw,
    const float* __restrict__ rc, const float* __restrict__ w,
    const float* __restrict__ bias, const float* __restrict__ sb,
    const short* __restrict__ bimg, float* __restrict__ out,
    float* __restrict__ part) {
  constexpr int SPLC = NSTEPS / KS;
  // A: [128 m][64 k] bf16, slot ^= m&7.  B: [512 n][64 k] bf16, slot ^= n&7.
  __shared__ __align__(16) short A_lds[2][A_SH];   // 32 KB
  __shared__ __align__(16) short B_lds[2][B_SH];   // 128 KB  (total 160 KB)

  const int t = threadIdx.x, lane = t & 63, wid = t >> 6;
  const int wm = wid >> 2;        // 0..1 : 64 m-rows per wave
  const int wn = wid & 3;         // 0..3 : 128 n-cols per wave
  const int l15 = lane & 15, kb = lane >> 4;
  const int m0 = blockIdx.x * BM;
  const int ks = (KS > 1) ? blockIdx.y : 0;
  const int s0 = ks * SPLC;

  const int a_il = t & 7;         // k-octet
  const int a_m = t >> 3;         // A rows a_m and a_m+64
  const float c2 = -10.2591705f;  // -(8/3)^2 * log2(e)

  f32x4 acc[4][8];
#pragma unroll
  for (int i = 0; i < 4; ++i)
#pragma unroll
    for (int j = 0; j < 8; ++j) acc[i][j] = (f32x4){0.f, 0.f, 0.f, 0.f};

  // ---- single-step-lookahead register state (loaded top of step, used mid-step) --
  float xrA, xrB;                 // phi x (rows a_m, a_m+64)
  float4 pr0, pr1, pc0, pc1;      // rbf params
  float4 cA0, cA1, cB0, cB1;      // cos x

  auto loadNext = [&](int s1) {
    if (s1 < PHI_STEPS) {
      const int feat = s1 * 8 + a_il;
      xrA = x[(size_t)(m0 + a_m) * IN_F + feat];
      xrB = x[(size_t)(m0 + a_m + 64) * IN_F + feat];
      pr0 = *(const float4*)(rw + feat * 8);
      pr1 = *(const float4*)(rw + feat * 8 + 4);
      pc0 = *(const float4*)(rc + feat * 8);
      pc1 = *(const float4*)(rc + feat * 8 + 4);
    } else {
      const float* xpA = x + (size_t)(m0 + a_m) * IN_F + (s1 - PHI_STEPS) * 64 + a_il * 8;
      const float* xpB = xpA + (size_t)64 * IN_F;
      cA0 = *(const float4*)xpA; cA1 = *(const float4*)(xpA + 4);
      cB0 = *(const float4*)xpB; cB1 = *(const float4*)(xpB + 4);
    }
  };

  auto writeA = [&](int s1, short* __restrict__ Ad) {
    short8 avA, avB;
    if (s1 < PHI_STEPS) {
      const float rwv[8] = {pr0.x, pr0.y, pr0.z, pr0.w, pr1.x, pr1.y, pr1.z, pr1.w};
      const float rcv[8] = {pc0.x, pc0.y, pc0.z, pc0.w, pc1.x, pc1.y, pc1.z, pc1.w};
#pragma unroll
      for (int b = 0; b < 8; ++b) {
        const float zA = fmaf(xrA, rwv[b], -rcv[b]);
        const float zB = fmaf(xrB, rwv[b], -rcv[b]);
        avA[b] = f2bf(exp2f(c2 * zA * zA));
        avB[b] = f2bf(exp2f(c2 * zB * zB));
      }
    } else {
      avA[0] = f2bf(__cosf(cA0.x)); avA[1] = f2bf(__cosf(cA0.y));
      avA[2] = f2bf(__cosf(cA0.z)); avA[3] = f2bf(__cosf(cA0.w));
      avA[4] = f2bf(__cosf(cA1.x)); avA[5] = f2bf(__cosf(cA1.y));
      avA[6] = f2bf(__cosf(cA1.z)); avA[7] = f2bf(__cosf(cA1.w));
      avB[0] = f2bf(__cosf(cB0.x)); avB[1] = f2bf(__cosf(cB0.y));
      avB[2] = f2bf(__cosf(cB0.z)); avB[3] = f2bf(__cosf(cB0.w));
      avB[4] = f2bf(__cosf(cB1.x)); avB[5] = f2bf(__cosf(cB1.y));
      avB[6] = f2bf(__cosf(cB1.z)); avB[7] = f2bf(__cosf(cB1.w));
    }
    const int mA = a_m, mB = a_m + 64;
    *(short8*)&Ad[mA * BK + (a_il ^ (mA & 7)) * 8] = avA;
    *(short8*)&Ad[mB * BK + (a_il ^ (mB & 7)) * 8] = avB;
  };

  auto stageB = [&](int s, short* __restrict__ Bd) {
    if (PREB) {
      const short* src = bimg + ((size_t)s * IMG_CHUNKS + t) * 8;
#pragma unroll
      for (int c = 0; c < 8; ++c)
        glds16(src + (size_t)c * 512 * 8, Bd + c * 4096 + wid * 512);
    } else {
#pragma unroll
      for (int c = 0; c < 8; ++c) {
        const int ci = c * 512 + t;
        const int n = ci >> 3, slot = ci & 7, oct = slot ^ (n & 7);
        short8 v;
#pragma unroll
        for (int j = 0; j < 8; ++j) v[j] = f2bf(bsrc(w, sb, s * 64 + oct * 8 + j, n));
        *(short8*)&Bd[ci * 8] = v;
      }
    }
  };

  auto mfma_half = [&](const short* __restrict__ Ab, const short* __restrict__ Bb,
                       int kk) {
    const int sk = kk * 4 + kb;
    short8 af[4], bf[8];
#pragma unroll
    for (int mi = 0; mi < 4; ++mi) {
      const int r = wm * 64 + mi * 16 + l15;
      af[mi] = *(const short8*)&Ab[r * BK + (sk ^ (r & 7)) * 8];
    }
#pragma unroll
    for (int ni = 0; ni < 8; ++ni) {
      const int n = wn * 128 + ni * 16 + l15;
      bf[ni] = *(const short8*)&Bb[n * BK + (sk ^ (n & 7)) * 8];
    }
#pragma unroll
    for (int mi = 0; mi < 4; ++mi)
#pragma unroll
      for (int ni = 0; ni < 8; ++ni)
        acc[mi][ni] = __builtin_amdgcn_mfma_f32_16x16x32_bf16(
            af[mi], bf[ni], acc[mi][ni], 0, 0, 0);
  };

  // ---------------- prologue ----------------
  stageB(s0, B_lds[0]);
  loadNext(s0);
  writeA(s0, A_lds[0]);
  __syncthreads();

  // ---------------- main loop: stage(s+1) || mfma(s), one barrier/step --------
  for (int si = 0; si < SPLC; ++si) {
    const int c = si & 1;
    const int s = s0 + si;
    if (si + 1 < SPLC) { stageB(s + 1, B_lds[c ^ 1]); loadNext(s + 1); }
    mfma_half(A_lds[c], B_lds[c], 0);
    if (si + 1 < SPLC) writeA(s + 1, A_lds[c ^ 1]);
    mfma_half(A_lds[c], B_lds[c], 1);
    __syncthreads();
  }

  // ---------------- epilogue ----------------
#pragma unroll
  for (int ni = 0; ni < 8; ++ni) {
    const int col = wn * 128 + ni * 16 + l15;
    const float bb = (KS == 1 || ks == 0) ? bias[col] : 0.f;
#pragma unroll
    for (int mi = 0; mi < 4; ++mi) {
      const int rb = m0 + wm * 64 + mi * 16 + kb * 4;
#pragma unroll
      for (int r4 = 0; r4 < 4; ++r4) {
        const size_t idx = (size_t)(rb + r4) * OUT_F + col;
        if (KS == 1 || ks == 0) out[idx] = acc[mi][ni][r4] + bb;
        else                    part[(size_t)(ks - 1) * PART_ELEMS + idx] = acc[mi][ni][r4];
      }
    }
  }
}

extern "C" void kernel_launch(void* const* d_in, const int* in_sizes, int n_in,
                              void* d_out, int out_size, void* d_ws, size_t ws_size,
                              hipStream_t stream) {
  const float* x    = (const float*)d_in[0];
  const float* rw   = (const float*)d_in[1];
  const float* rc   = (const float*)d_in[2];
  const float* w    = (const float*)d_in[3];
  const float* bias = (const float*)d_in[4];
  const float* sb   = (const float*)d_in[5];
  float* out = (float*)d_out;

  const int nrows = in_sizes[0] / IN_F;  // 8192
  const int mb = nrows / BM;             // 64

  const size_t img_bytes  = (size_t)NSTEPS * IMG_CHUNKS * 16;    // 4.72 MB
  const size_t part_bytes = (size_t)PART_ELEMS * sizeof(float);  // 16.8 MB
  const int img_chunks_total = NSTEPS * IMG_CHUNKS;

  if (ws_size >= img_bytes + 3 * part_bytes) {
    // KSPLIT=4: 256 blocks (1/CU), 18 steps each; 3 partial planes + reduce.
    short* img = (short*)d_ws;
    float* part = (float*)((char*)d_ws + img_bytes);
    prep_b<<<img_chunks_total / 256, 256, 0, stream>>>(w, sb, img);
    kan_main<4, true><<<dim3(mb, 4), THREADS, 0, stream>>>(x, rw, rc, w, bias, sb,
                                                           img, out, part);
    reduce_add<3><<<2048, 256, 0, stream>>>(part, out);
  } else if (ws_size >= img_bytes + part_bytes) {
    short* img = (short*)d_ws;
    float* part = (float*)((char*)d_ws + img_bytes);
    prep_b<<<img_chunks_total / 256, 256, 0, stream>>>(w, sb, img);
    kan_main<2, true><<<dim3(mb, 2), THREADS, 0, stream>>>(x, rw, rc, w, bias, sb,
                                                           img, out, part);
    reduce_add<1><<<2048, 256, 0, stream>>>(part, out);
  } else if (ws_size >= part_bytes) {
    float* part = (float*)d_ws;
    kan_main<2, false><<<dim3(mb, 2), THREADS, 0, stream>>>(x, rw, rc, w, bias, sb,
                                                            nullptr, out, part);
    reduce_add<1><<<2048, 256, 0, stream>>>(part, out);
  } else {
    kan_main<1, false><<<dim3(mb, 1), THREADS, 0, stream>>>(x, rw, rc, w, bias, sb,
                                                            nullptr, out, nullptr);
  }
}